// Round 13
// baseline (148.837 us; speedup 1.0000x reference)
//
#include <hip/hip_runtime.h>
#include <math.h>

#define SQ 1024
#define DIM 1024
#define NH 16
#define HDIM 64

typedef short bf16x8 __attribute__((ext_vector_type(8)));
typedef float f32x4 __attribute__((ext_vector_type(4)));

// RNE fp32->bf16 (bit-identical to hardware v_cvt rounding for non-NaN)
__device__ __forceinline__ unsigned short f2bf(float x) {
  unsigned int u = __builtin_bit_cast(unsigned int, x);
  u += 0x7FFFu + ((u >> 16) & 1u);
  return (unsigned short)(u >> 16);
}
__device__ __forceinline__ unsigned int pkbf(float a, float b) {
  return (unsigned)f2bf(a) | ((unsigned)f2bf(b) << 16);
}

// ---------- prep: convert 7 fp32 matrices to bf16 pool + relpos table ----------
__global__ __launch_bounds__(256) void prep_kernel(
    const float* __restrict__ query, const float* __restrict__ key_,
    const float* __restrict__ value, const float* __restrict__ Wq,
    const float* __restrict__ Wk, const float* __restrict__ Wv,
    const float* __restrict__ Wo, unsigned short* __restrict__ bfin,
    unsigned short* __restrict__ Rc)
{
  const int b = blockIdx.x;
  if (b < 3584) {
    int gid = b * 256 + threadIdx.x;        // 917504 threads
    int seg = gid >> 17;                    // 131072 threads per segment
    int off = (gid & 131071) * 8;
    const float* s = seg == 0 ? query : seg == 1 ? key_ : seg == 2 ? value :
                     seg == 3 ? Wq : seg == 4 ? Wk : seg == 5 ? Wv : Wo;
    float4 a = *(const float4*)&s[off];
    float4 c = *(const float4*)&s[off + 4];
    uint4 o;
    o.x = pkbf(a.x, a.y); o.y = pkbf(a.z, a.w);
    o.z = pkbf(c.x, c.y); o.w = pkbf(c.z, c.w);
    *(uint4*)&bfin[(size_t)gid * 8] = o;
  } else {
    int gid = (b - 3584) * 256 + threadIdx.x;  // 65536 = 2048 p x 32 f
    int p = gid >> 5, f = gid & 31;
    float pos = (float)(p - (SQ - 1));
    float invf = expf(-0.28782313662425575f * (float)f);   // 10000^(-f/32)
    float ang = pos * invf;
    Rc[p * HDIM + 2 * f]     = f2bf(sinf(ang));
    Rc[p * HDIM + 2 * f + 1] = f2bf(cosf(ang));
  }
}

// ---------- merged Q/K/V projection GEMM, reg-prefetch + LDS double buffer ----------
__global__ __launch_bounds__(256) void gemm_qkv(
    const unsigned short* __restrict__ bfin,
    unsigned short* __restrict__ qu, unsigned short* __restrict__ qv,
    unsigned short* __restrict__ kkp, unsigned short* __restrict__ vvpT,
    const float* __restrict__ u, const float* __restrict__ v)
{
  __shared__ short As[2][64 * 72];
  __shared__ short Bs[2][64 * 72];
  const int z = blockIdx.z;
  const unsigned short* A = bfin + (size_t)z * (1 << 20);        // q / k / v
  const unsigned short* B = bfin + (size_t)(3 + z) * (1 << 20);  // Wq / Wk / Wv
  const int tid = threadIdx.x;
  const int bm = blockIdx.y * 64, bn = blockIdx.x * 64;
  const int w = tid >> 6, l = tid & 63, g = l >> 4, q = l & 15;
  const int wr = w >> 1, wc = w & 1;
  const int srow = tid >> 2, sc = (tid & 3) * 16;
  const unsigned short* Arow = A + (bm + srow) * DIM + sc;
  const unsigned short* Brow = B + (bn + srow) * DIM + sc;
  f32x4 acc[2][2] = {};

  uint4 a0 = *(const uint4*)&Arow[0];
  uint4 a1 = *(const uint4*)&Arow[8];
  uint4 b0 = *(const uint4*)&Brow[0];
  uint4 b1 = *(const uint4*)&Brow[8];
  *(uint4*)&As[0][srow * 72 + sc]     = a0;
  *(uint4*)&As[0][srow * 72 + sc + 8] = a1;
  *(uint4*)&Bs[0][srow * 72 + sc]     = b0;
  *(uint4*)&Bs[0][srow * 72 + sc + 8] = b1;
  __syncthreads();

  #pragma unroll 2
  for (int k0 = 0; k0 < DIM; k0 += 64) {
    const int cur = (k0 >> 6) & 1;
    const bool more = (k0 + 64 < DIM);
    if (more) {
      a0 = *(const uint4*)&Arow[k0 + 64];
      a1 = *(const uint4*)&Arow[k0 + 64 + 8];
      b0 = *(const uint4*)&Brow[k0 + 64];
      b1 = *(const uint4*)&Brow[k0 + 64 + 8];
    }
    #pragma unroll
    for (int ks = 0; ks < 2; ks++) {
      bf16x8 fa0 = *(const bf16x8*)&As[cur][(wr * 32 + q) * 72      + ks * 32 + g * 8];
      bf16x8 fa1 = *(const bf16x8*)&As[cur][(wr * 32 + 16 + q) * 72 + ks * 32 + g * 8];
      bf16x8 fb0 = *(const bf16x8*)&Bs[cur][(wc * 32 + q) * 72      + ks * 32 + g * 8];
      bf16x8 fb1 = *(const bf16x8*)&Bs[cur][(wc * 32 + 16 + q) * 72 + ks * 32 + g * 8];
      acc[0][0] = __builtin_amdgcn_mfma_f32_16x16x32_bf16(fa0, fb0, acc[0][0], 0, 0, 0);
      acc[0][1] = __builtin_amdgcn_mfma_f32_16x16x32_bf16(fa0, fb1, acc[0][1], 0, 0, 0);
      acc[1][0] = __builtin_amdgcn_mfma_f32_16x16x32_bf16(fa1, fb0, acc[1][0], 0, 0, 0);
      acc[1][1] = __builtin_amdgcn_mfma_f32_16x16x32_bf16(fa1, fb1, acc[1][1], 0, 0, 0);
    }
    if (more) {
      *(uint4*)&As[cur ^ 1][srow * 72 + sc]     = a0;
      *(uint4*)&As[cur ^ 1][srow * 72 + sc + 8] = a1;
      *(uint4*)&Bs[cur ^ 1][srow * 72 + sc]     = b0;
      *(uint4*)&Bs[cur ^ 1][srow * 72 + sc + 8] = b1;
      __syncthreads();
    }
  }

  #pragma unroll
  for (int i = 0; i < 2; i++) {
    #pragma unroll
    for (int j = 0; j < 2; j++) {
      const int m0 = bm + wr * 32 + i * 16 + g * 4;
      const int n  = bn + wc * 32 + j * 16 + q;
      if (z == 0) {
        float uu = u[n], vv = v[n];
        #pragma unroll
        for (int r = 0; r < 4; r++) {
          qu[(m0 + r) * DIM + n] = f2bf((acc[i][j][r] + uu) * 0.125f);
          qv[(m0 + r) * DIM + n] = f2bf((acc[i][j][r] + vv) * 0.125f);
        }
      } else if (z == 1) {
        #pragma unroll
        for (int r = 0; r < 4; r++)
          kkp[(m0 + r) * DIM + n] = f2bf(acc[i][j][r]);
      } else {
        ushort4 pk;
        pk.x = f2bf(acc[i][j][0]); pk.y = f2bf(acc[i][j][1]);
        pk.z = f2bf(acc[i][j][2]); pk.w = f2bf(acc[i][j][3]);
        *(ushort4*)&vvpT[n * SQ + m0] = pk;           // vvpT[d][t]
      }
    }
  }
}

// ---------- output GEMM: 32x64 tiles (512 blocks, 2 blocks/CU) ----------
// FIXED: staging now writes TWO uint4s (16 shorts) per thread, matching the
// 16-short LDS offsets. Round 10/11/12's version wrote only one -> garbage LDS.
__global__ __launch_bounds__(256) void gemm_out(
    const unsigned short* __restrict__ A, const unsigned short* __restrict__ B,
    float* __restrict__ out, const float* __restrict__ bo)
{
  __shared__ short As[2][32 * 72];
  __shared__ short Bs[2][64 * 72];
  const int tid = threadIdx.x;
  const int bm = blockIdx.y * 32, bn = blockIdx.x * 64;
  const int w = tid >> 6, l = tid & 63, g = l >> 4, q = l & 15;
  const int wr = w >> 1, wc = w & 1;     // wave: rows wr*16..+16, cols wc*32..+32
  const int srowB = tid >> 2, scB = (tid & 3) * 16;
  const int srowA = (tid & 127) >> 2, scA = (tid & 3) * 16;
  const bool doA = (tid < 128);
  const unsigned short* ArowP = A + (bm + srowA) * DIM + scA;
  const unsigned short* BrowP = B + (bn + srowB) * DIM + scB;
  f32x4 acc[2] = {};

  uint4 a0 = {}, a1 = {};
  uint4 b0 = *(const uint4*)&BrowP[0];
  uint4 b1 = *(const uint4*)&BrowP[8];
  if (doA) {
    a0 = *(const uint4*)&ArowP[0];
    a1 = *(const uint4*)&ArowP[8];
    *(uint4*)&As[0][srowA * 72 + scA]     = a0;
    *(uint4*)&As[0][srowA * 72 + scA + 8] = a1;
  }
  *(uint4*)&Bs[0][srowB * 72 + scB]     = b0;
  *(uint4*)&Bs[0][srowB * 72 + scB + 8] = b1;
  __syncthreads();

  #pragma unroll 2
  for (int k0 = 0; k0 < DIM; k0 += 64) {
    const int cur = (k0 >> 6) & 1;
    const bool more = (k0 + 64 < DIM);
    if (more) {
      if (doA) {
        a0 = *(const uint4*)&ArowP[k0 + 64];
        a1 = *(const uint4*)&ArowP[k0 + 64 + 8];
      }
      b0 = *(const uint4*)&BrowP[k0 + 64];
      b1 = *(const uint4*)&BrowP[k0 + 64 + 8];
    }
    #pragma unroll
    for (int ks = 0; ks < 2; ks++) {
      bf16x8 fa  = *(const bf16x8*)&As[cur][(wr * 16 + q) * 72      + ks * 32 + g * 8];
      bf16x8 fb0 = *(const bf16x8*)&Bs[cur][(wc * 32 + q) * 72      + ks * 32 + g * 8];
      bf16x8 fb1 = *(const bf16x8*)&Bs[cur][(wc * 32 + 16 + q) * 72 + ks * 32 + g * 8];
      acc[0] = __builtin_amdgcn_mfma_f32_16x16x32_bf16(fa, fb0, acc[0], 0, 0, 0);
      acc[1] = __builtin_amdgcn_mfma_f32_16x16x32_bf16(fa, fb1, acc[1], 0, 0, 0);
    }
    if (more) {
      __syncthreads();
      if (doA) {
        *(uint4*)&As[cur ^ 1][srowA * 72 + scA]     = a0;
        *(uint4*)&As[cur ^ 1][srowA * 72 + scA + 8] = a1;
      }
      *(uint4*)&Bs[cur ^ 1][srowB * 72 + scB]     = b0;
      *(uint4*)&Bs[cur ^ 1][srowB * 72 + scB + 8] = b1;
      __syncthreads();
    }
  }

  #pragma unroll
  for (int j = 0; j < 2; j++) {
    const int m0 = bm + wr * 16 + g * 4;
    const int n  = bn + wc * 32 + j * 16 + q;
    float bb = bo[n];
    #pragma unroll
    for (int r = 0; r < 4; r++)
      out[(m0 + r) * DIM + n] = acc[j][r] + bb;
  }
}

// ---------- fused attention: 8 waves, in-block split-t + in-block combine ----------
// Waves 0-3: t in [0,512); waves 4-7: t in [512,1024). Per-group K/V/P/G LDS.
// Rc MFMA fragments are loaded directly from global (L2-resident 256 KB table).
__global__ __launch_bounds__(512) void attn_mfma(
    const unsigned short* __restrict__ qu, const unsigned short* __restrict__ qv,
    const unsigned short* __restrict__ kkp, const unsigned short* __restrict__ vvpT,
    const unsigned short* __restrict__ Rc, unsigned short* __restrict__ attout)
{
  __shared__ short Ks[2][64 * 72];   // K tile  [t][d] per group
  __shared__ short Vs[2][64 * 72];   // V^T tile [d][t] per group
  __shared__ short Ps[2][64 * 72];   // P  [s][t] per group
  __shared__ float Gs[2][64 * 84];   // G  [s][p_rel]; becomes partial-O after loop
  __shared__ float2 mlS[2][64];      // per-row (m, l)

  const int tid = threadIdx.x;
  const int h  = blockIdx.x >> 4;
  const int s0 = (blockIdx.x & 15) * 64;
  const int w = tid >> 6, th = w >> 2, ws = w & 3;
  const int l = tid & 63, g = l >> 4, q = l & 15;
  const int col0 = h * HDIM;

  const int sw = s0 + ws * 16 + q;
  bf16x8 qub[2], qvb[2];
  qub[0] = *(const bf16x8*)&qu[sw * DIM + col0 + g * 8];
  qub[1] = *(const bf16x8*)&qu[sw * DIM + col0 + 32 + g * 8];
  qvb[0] = *(const bf16x8*)&qv[sw * DIM + col0 + g * 8];
  qvb[1] = *(const bf16x8*)&qv[sw * DIM + col0 + 32 + g * 8];

  f32x4 accO[4] = {};
  float m_run = -1e30f, l_run = 0.f;

  const int tid8 = tid & 255;                 // group-local thread id
  const int srow = tid8 >> 2, sc = (tid8 & 3) * 16;
  const int tstart = th * 512, tend = tstart + 512;

  uint4 kr0, kr1, vr0, vr1;
  {
    kr0 = *(const uint4*)&kkp[(tstart + srow) * DIM + col0 + sc];
    kr1 = *(const uint4*)&kkp[(tstart + srow) * DIM + col0 + sc + 8];
    vr0 = *(const uint4*)&vvpT[(col0 + srow) * SQ + tstart + sc];
    vr1 = *(const uint4*)&vvpT[(col0 + srow) * SQ + tstart + sc + 8];
    *(uint4*)&Ks[th][srow * 72 + sc]     = kr0;
    *(uint4*)&Ks[th][srow * 72 + sc + 8] = kr1;
    *(uint4*)&Vs[th][srow * 72 + sc]     = vr0;
    *(uint4*)&Vs[th][srow * 72 + sc + 8] = vr1;
  }
  __syncthreads();

  for (int t0 = tstart; t0 < tend; t0 += 64) {
    const bool more = (t0 + 64 < tend);
    if (more) {
      const int tn = t0 + 64;
      kr0 = *(const uint4*)&kkp[(tn + srow) * DIM + col0 + sc];
      kr1 = *(const uint4*)&kkp[(tn + srow) * DIM + col0 + sc + 8];
      vr0 = *(const uint4*)&vvpT[(col0 + srow) * SQ + tn + sc];
      vr1 = *(const uint4*)&vvpT[(col0 + srow) * SQ + tn + sc + 8];
    }
    const int P0 = s0 - t0 + 960;   // Rc band base for this tile

    f32x4 accS[4] = {};
    f32x4 accG[5] = {};
    #pragma unroll
    for (int ks = 0; ks < 2; ks++) {
      #pragma unroll
      for (int tf = 0; tf < 4; tf++) {
        bf16x8 a = *(const bf16x8*)&Ks[th][(tf * 16 + q) * 72 + ks * 32 + g * 8];
        accS[tf] = __builtin_amdgcn_mfma_f32_16x16x32_bf16(a, qub[ks], accS[tf], 0, 0, 0);
      }
      #pragma unroll
      for (int pf = 0; pf < 5; pf++) {
        bf16x8 a = *(const bf16x8*)&Rc[(size_t)(P0 + ws * 16 + pf * 16 + q) * HDIM + ks * 32 + g * 8];
        accG[pf] = __builtin_amdgcn_mfma_f32_16x16x32_bf16(a, qvb[ks], accG[pf], 0, 0, 0);
      }
    }
    #pragma unroll
    for (int pf = 0; pf < 5; pf++)
      *(f32x4*)&Gs[th][(ws * 16 + q) * 84 + pf * 16 + g * 4] = accG[pf];

    float pvals[16];
    float mx = -1e30f;
    #pragma unroll
    for (int tf = 0; tf < 4; tf++) {
      #pragma unroll
      for (int r = 0; r < 4; r++) {
        int t_rel = tf * 16 + g * 4 + r;
        float sval = accS[tf][r] + Gs[th][(ws * 16 + q) * 84 + (q - t_rel + 63)];
        pvals[tf * 4 + r] = sval;
        mx = fmaxf(mx, sval);
      }
    }
    mx = fmaxf(mx, __shfl_xor(mx, 16));
    mx = fmaxf(mx, __shfl_xor(mx, 32));
    float m_new = fmaxf(m_run, mx);
    float scale = __expf(m_run - m_new);
    float rsum = 0.f;
    #pragma unroll
    for (int i = 0; i < 16; i++) {
      float p = __expf(pvals[i] - m_new);
      pvals[i] = p;
      rsum += p;
    }
    rsum += __shfl_xor(rsum, 16);
    rsum += __shfl_xor(rsum, 32);
    l_run = l_run * scale + rsum;
    m_run = m_new;
    #pragma unroll
    for (int df = 0; df < 4; df++) {
      #pragma unroll
      for (int r = 0; r < 4; r++) accO[df][r] *= scale;
    }
    #pragma unroll
    for (int tf = 0; tf < 4; tf++) {
      unsigned int lo = pkbf(pvals[tf * 4 + 0], pvals[tf * 4 + 1]);
      unsigned int hi = pkbf(pvals[tf * 4 + 2], pvals[tf * 4 + 3]);
      *(uint2*)&Ps[th][(ws * 16 + q) * 72 + tf * 16 + g * 4] = make_uint2(lo, hi);
    }
    #pragma unroll
    for (int ks = 0; ks < 2; ks++) {
      bf16x8 b = *(const bf16x8*)&Ps[th][(ws * 16 + q) * 72 + ks * 32 + g * 8];
      #pragma unroll
      for (int df = 0; df < 4; df++) {
        bf16x8 a = *(const bf16x8*)&Vs[th][(df * 16 + q) * 72 + ks * 32 + g * 8];
        accO[df] = __builtin_amdgcn_mfma_f32_16x16x32_bf16(a, b, accO[df], 0, 0, 0);
      }
    }

    if (more) {
      __syncthreads();   // all waves done reading Ks/Vs
      *(uint4*)&Ks[th][srow * 72 + sc]     = kr0;
      *(uint4*)&Ks[th][srow * 72 + sc + 8] = kr1;
      *(uint4*)&Vs[th][srow * 72 + sc]     = vr0;
      *(uint4*)&Vs[th][srow * 72 + sc + 8] = vr1;
      __syncthreads();   // tile ready
    }
  }

  // deposit raw partial O into the (now-dead) Gs region; rows are wave-private
  {
    float* Os = (float*)&Gs[th][0];
    const int sl = ws * 16 + q;
    #pragma unroll
    for (int df = 0; df < 4; df++)
      *(f32x4*)&Os[sl * 84 + df * 16 + g * 4] = accO[df];
    if (g == 0) mlS[th][sl] = make_float2(m_run, l_run);
  }
  __syncthreads();

  // in-block combine of the two t-halves -> attout (bf16)
  {
    const int s = tid >> 3, d0 = (tid & 7) * 8;
    float2 Am = mlS[0][s], Bm = mlS[1][s];
    float m = fmaxf(Am.x, Bm.x);
    float wA = __expf(Am.x - m), wB = __expf(Bm.x - m);
    float inv = 1.f / (Am.y * wA + Bm.y * wB);
    wA *= inv; wB *= inv;
    const float* OsA = (const float*)&Gs[0][0];
    const float* OsB = (const float*)&Gs[1][0];
    float4 a0 = *(const float4*)&OsA[s * 84 + d0];
    float4 a1 = *(const float4*)&OsA[s * 84 + d0 + 4];
    float4 b0 = *(const float4*)&OsB[s * 84 + d0];
    float4 b1 = *(const float4*)&OsB[s * 84 + d0 + 4];
    uint4 o;
    o.x = pkbf(a0.x * wA + b0.x * wB, a0.y * wA + b0.y * wB);
    o.y = pkbf(a0.z * wA + b0.z * wB, a0.w * wA + b0.w * wB);
    o.z = pkbf(a1.x * wA + b1.x * wB, a1.y * wA + b1.y * wB);
    o.w = pkbf(a1.z * wA + b1.z * wB, a1.w * wA + b1.w * wB);
    *(uint4*)&attout[(s0 + s) * DIM + col0 + d0] = o;
  }
}

extern "C" void kernel_launch(void* const* d_in, const int* in_sizes, int n_in,
                              void* d_out, int out_size, void* d_ws, size_t ws_size,
                              hipStream_t stream) {
  const float* value = (const float*)d_in[0];
  const float* key   = (const float*)d_in[1];
  const float* query = (const float*)d_in[2];
  const float* Wq    = (const float*)d_in[3];
  const float* Wk    = (const float*)d_in[4];
  const float* Wv    = (const float*)d_in[5];
  const float* u     = (const float*)d_in[6];
  const float* v     = (const float*)d_in[7];
  const float* Wo    = (const float*)d_in[8];
  const float* bo    = (const float*)d_in[9];
  float* out = (float*)d_out;

  unsigned short* ws = (unsigned short*)d_ws;
  unsigned short* bfin   = ws;                       // 7 x 1M bf16: q,k,v,Wq,Wk,Wv,Wo
  unsigned short* qu_p   = bfin   + 7 * (1 << 20);
  unsigned short* qv_p   = qu_p   + (1 << 20);
  unsigned short* kkp    = qv_p   + (1 << 20);
  unsigned short* vvpT   = kkp    + (1 << 20);
  unsigned short* attout = vvpT   + (1 << 20);
  unsigned short* Rc     = attout + (1 << 20);       // 2048*64

  prep_kernel<<<3840, 256, 0, stream>>>(query, key, value, Wq, Wk, Wv, Wo, bfin, Rc);

  dim3 gqkv(16, 16, 3);
  gemm_qkv<<<gqkv, 256, 0, stream>>>(bfin, qu_p, qv_p, kkp, vvpT, u, v);

  attn_mfma<<<NH * (SQ / 64), 512, 0, stream>>>(qu_p, qv_p, kkp, vvpT, Rc, attout);

  dim3 ggo(16, 32);
  gemm_out<<<ggo, 256, 0, stream>>>(attout, bfin + 6 * (1 << 20), out, bo);
}